// Round 23
// baseline (180.980 us; speedup 1.0000x reference)
//
#include <hip/hip_runtime.h>
#include <hip/hip_fp16.h>

#define N_NODES 50000
#define N_EDGES 800000
#define E2 (N_EDGES + N_NODES)   // 850000 edges incl self-loops

#define BSHIFT 6
#define BMASK 63
#define NBUCK 782            // ceil(50000/64) buckets of 64 dst each
#define EPB 4096             // edges per block in counting sort
#define NBLKC 208            // ceil(E2/EPB)
#define CSBLK 196            // colscan blocks (4 buckets each)
#define G1BLK 391            // gemm1 blocks (128 rows each)

typedef _Float16 h8v __attribute__((ext_vector_type(8)));
typedef float f4v __attribute__((ext_vector_type(4)));

// ---------------- CSR build: counting sort (no global atomics) ----------------

// phase A: per-block LDS histogram -> gh[blk][b]; block NBLKC preps W1T
__global__ __launch_bounds__(256) void k_hist(const int* __restrict__ ei,
        int* __restrict__ gh, const float* __restrict__ W1, _Float16* __restrict__ W1T) {
    if (blockIdx.x == NBLKC) {   // W1 transpose+fp16: W1T[c][k] = W1[k][c]
        for (int i = threadIdx.x; i < 128 * 256; i += 256) {
            int c = i >> 8, k = i & 255;
            W1T[i] = (_Float16)W1[k * 128 + c];
        }
        return;
    }
    __shared__ int h[NBUCK];
    int tid = threadIdx.x;
    for (int b = tid; b < NBUCK; b += 256) h[b] = 0;
    __syncthreads();
    int base = blockIdx.x * EPB;
    for (int i = tid; i < EPB; i += 256) {
        int e = base + i;
        if (e < E2) {
            int dst = (e < N_EDGES) ? ei[N_EDGES + e] : (e - N_EDGES);
            atomicAdd(&h[dst >> BSHIFT], 1);
        }
    }
    __syncthreads();
    for (int b = tid; b < NBUCK; b += 256) gh[blockIdx.x * NBUCK + b] = h[b];
}

// fused: blocks [0,CSBLK) = colscan (per-bucket scan across blocks);
//        blocks [CSBLK, CSBLK+G1BLK) = GEMM1 MFMA (independent of CSR).
__global__ __launch_bounds__(256) void k_csg(int* __restrict__ gh,
        int* __restrict__ tot, const float* __restrict__ x,
        const _Float16* __restrict__ W1T, _Float16* __restrict__ h1h) {
    if (blockIdx.x < CSBLK) {
        // ---- colscan ----
        int wave = threadIdx.x >> 6, lane = threadIdx.x & 63;
        int b = blockIdx.x * 4 + wave;
        if (b >= NBUCK) return;
        int carry = 0;
        for (int c = 0; c < NBLKC; c += 64) {
            int k = c + lane;
            int v = (k < NBLKC) ? gh[k * NBUCK + b] : 0;
            int xv = v;
            #pragma unroll
            for (int o = 1; o < 64; o <<= 1) { int y = __shfl_up(xv, o); if (lane >= o) xv += y; }
            if (k < NBLKC) gh[k * NBUCK + b] = carry + xv - v;   // exclusive
            carry += __shfl(xv, 63);
        }
        if (lane == 0) tot[b] = carry;
        return;
    }
    // ---- GEMM1: 4 waves x 32 rows = 128 rows per block ----
    int gblk = blockIdx.x - CSBLK;
    int lane = threadIdx.x & 63;
    int wv = threadIdx.x >> 6;            // 0..3
    int rowbase = gblk * 128 + wv * 32;
    int r0 = lane & 15;
    int kg = lane >> 4;                   // 0..3
    f4v acc[2][8];
    #pragma unroll
    for (int i = 0; i < 2; ++i)
        #pragma unroll
        for (int j = 0; j < 8; ++j) acc[i][j] = (f4v)0.f;

    #pragma unroll 1
    for (int kt = 0; kt < 256; kt += 32) {
        h8v a[2];
        #pragma unroll
        for (int rf = 0; rf < 2; ++rf) {
            int row = rowbase + rf * 16 + r0;
            if (row >= N_NODES) row = N_NODES - 1;
            const float* ap = x + (size_t)row * 256 + kt + kg * 8;
            float4 lo = *(const float4*)ap;
            float4 hi = *(const float4*)(ap + 4);
            h8v t;
            t[0] = (_Float16)lo.x; t[1] = (_Float16)lo.y;
            t[2] = (_Float16)lo.z; t[3] = (_Float16)lo.w;
            t[4] = (_Float16)hi.x; t[5] = (_Float16)hi.y;
            t[6] = (_Float16)hi.z; t[7] = (_Float16)hi.w;
            a[rf] = t;
        }
        #pragma unroll
        for (int cf = 0; cf < 8; ++cf) {
            h8v b = *(const h8v*)(W1T + (size_t)(cf * 16 + r0) * 256 + kt + kg * 8);
            acc[0][cf] = __builtin_amdgcn_mfma_f32_16x16x32_f16(a[0], b, acc[0][cf], 0, 0, 0);
            acc[1][cf] = __builtin_amdgcn_mfma_f32_16x16x32_f16(a[1], b, acc[1][cf], 0, 0, 0);
        }
    }
    // C/D: col = lane&15, row = (lane>>4)*4 + reg
    #pragma unroll
    for (int rf = 0; rf < 2; ++rf) {
        #pragma unroll
        for (int r = 0; r < 4; ++r) {
            int row = rowbase + rf * 16 + kg * 4 + r;
            if (row < N_NODES) {
                _Float16* orow = h1h + (size_t)row * 128 + r0;
                #pragma unroll
                for (int cf = 0; cf < 8; ++cf)
                    orow[cf * 16] = (_Float16)acc[rf][cf][r];
            }
        }
    }
}

// fused: block 0 = btot (scan bucket totals -> boff, + W2 pad);
//        blocks >= 1 = logits1 (reads fp16 h1h).
__global__ __launch_bounds__(256) void k_mid(const int* __restrict__ tot,
        int* __restrict__ boff, const float* __restrict__ W2, float* __restrict__ W2p,
        const __half* __restrict__ h1h,
        const float* __restrict__ a1s, const float* __restrict__ a1d,
        float* __restrict__ s1s, float* __restrict__ s1d) {
    if (blockIdx.x == 0) {
        int t = threadIdx.x;
        for (int i = t; i < 128 * 48; i += 256) {
            int k = i / 48, c = i - k * 48;
            W2p[i] = (c < 47) ? W2[k * 47 + c] : 0.f;
        }
        int v4[4]; int s = 0;
        #pragma unroll
        for (int j = 0; j < 4; ++j) {
            int b2 = t * 4 + j;
            v4[j] = (b2 < NBUCK) ? tot[b2] : 0;
            s += v4[j];
        }
        int lane = t & 63, w = t >> 6;
        __shared__ int ws[4];
        int xv = s;
        #pragma unroll
        for (int o = 1; o < 64; o <<= 1) { int y = __shfl_up(xv, o); if (lane >= o) xv += y; }
        if (lane == 63) ws[w] = xv;
        __syncthreads();
        int add = 0;
        for (int j = 0; j < w; ++j) add += ws[j];
        int run = add + xv - s;
        #pragma unroll
        for (int j = 0; j < 4; ++j) {
            int b2 = t * 4 + j;
            if (b2 < NBUCK) boff[b2] = run;
            run += v4[j];
        }
        if (t == 255) boff[NBUCK] = run;   // == E2
        return;
    }
    int idx = (blockIdx.x - 1) * 256 + threadIdx.x;   // N*8
    if (idx >= N_NODES * 8) return;
    int n = idx >> 3, h = idx & 7;
    const __half2* hp2 = (const __half2*)(h1h + (size_t)n * 128 + h * 16);
    float ss = 0.f, sd = 0.f;
    #pragma unroll
    for (int c2 = 0; c2 < 8; ++c2) {
        float2 v = __half22float2(hp2[c2]);
        ss += v.x * a1s[h * 16 + 2 * c2] + v.y * a1s[h * 16 + 2 * c2 + 1];
        sd += v.x * a1d[h * 16 + 2 * c2] + v.y * a1d[h * 16 + 2 * c2 + 1];
    }
    s1s[idx] = ss;
    s1d[idx] = sd;
}

// phase C: deterministic placement (LDS ranks only)
__global__ __launch_bounds__(256) void k_place(const int* __restrict__ ei,
        const int* __restrict__ gh, const int* __restrict__ boff,
        unsigned int* __restrict__ brec) {
    __shared__ int sbase[NBUCK];
    __shared__ int cnt[NBUCK];
    int tid = threadIdx.x;
    for (int b = tid; b < NBUCK; b += 256) {
        sbase[b] = boff[b] + gh[blockIdx.x * NBUCK + b];
        cnt[b] = 0;
    }
    __syncthreads();
    int base = blockIdx.x * EPB;
    for (int i = tid; i < EPB; i += 256) {
        int e = base + i;
        if (e < E2) {
            int src, dst;
            if (e < N_EDGES) { src = ei[e]; dst = ei[N_EDGES + e]; }
            else             { src = dst = e - N_EDGES; }
            int b = dst >> BSHIFT;
            int r = atomicAdd(&cnt[b], 1);
            brec[sbase[b] + r] = ((unsigned int)(dst & BMASK) << 16) | (unsigned int)src;
        }
    }
}

// per-bucket finalize: LDS histogram/scan/scatter -> coalesced csr write + offs
__global__ __launch_bounds__(256) void k_finalize(const unsigned int* __restrict__ brec,
        const int* __restrict__ boff, unsigned short* __restrict__ csr_src,
        int* __restrict__ offs) {
    int B = blockIdx.x;
    int tid = threadIdx.x;
    int base = boff[B];
    int total = boff[B + 1] - base;
    __shared__ int hist[64], cur[64];
    __shared__ unsigned short stage[2048];
    if (tid < 64) hist[tid] = 0;
    __syncthreads();
    const unsigned int* bp = brec + base;
    for (int i = tid; i < total; i += 256) atomicAdd(&hist[bp[i] >> 16], 1);
    __syncthreads();
    if (tid < 64) {   // wave 0: exclusive scan over 64 node-counts
        int v = hist[tid];
        int x = v;
        #pragma unroll
        for (int o = 1; o < 64; o <<= 1) { int y = __shfl_up(x, o); if (tid >= o) x += y; }
        int excl = x - v;
        cur[tid] = excl;
        int n = B * 64 + tid;
        if (n < N_NODES) offs[n] = base + excl;
    }
    if (B == NBUCK - 1 && tid == 0) offs[N_NODES] = boff[NBUCK];
    __syncthreads();
    if (total <= 2048) {
        for (int i = tid; i < total; i += 256) {
            unsigned int r = bp[i];
            int p = atomicAdd(&cur[r >> 16], 1);
            stage[p] = (unsigned short)(r & 0xFFFFu);
        }
        __syncthreads();
        for (int i = tid; i < total; i += 256) csr_src[base + i] = stage[i];
    } else {   // safety fallback (never hit for this graph)
        for (int i = tid; i < total; i += 256) {
            unsigned int r = bp[i];
            int p = atomicAdd(&cur[r >> 16], 1);
            csr_src[base + p] = (unsigned short)(r & 0xFFFFu);
        }
    }
}

// ------- layer-1 aggregate + bias + ELU (wave per node) -------
// 16-edge chunks, tail-trimmed gather (steps gated on remaining edges).

__global__ __launch_bounds__(256) void k_agg1(const __half* __restrict__ h1h,
        const float* __restrict__ s1s, const float* __restrict__ s1d,
        const int* __restrict__ offs, const unsigned short* __restrict__ csr_src,
        const float* __restrict__ b1, __half* __restrict__ h2o) {
    int wave = threadIdx.x >> 6;
    int lane = threadIdx.x & 63;
    int n = blockIdx.x * 4 + wave;   // N = 4*12500 exactly
    int beg = offs[n];
    int deg = offs[n + 1] - beg;     // >= 1 (self-loop)

    int h = lane & 7;        // head this lane evaluates exp for
    int slot = lane >> 3;    // edge slot within 8-sub-chunk (exp phase)
    int grp = lane >> 4;     // gather group 0..3
    int cidx = lane & 15;    // 16B channel block within row
    int hc = cidx >> 1;      // head of this lane's 8 channels
    float sdh = s1d[n * 8 + h];

    float dsum = 0.f;
    float acc[8] = {0.f, 0.f, 0.f, 0.f, 0.f, 0.f, 0.f, 0.f};
    for (int chunk = 0; chunk < deg; chunk += 16) {
        int rem = deg - chunk; if (rem > 16) rem = 16;
        int i0 = chunk + slot;
        int e0 = csr_src[beg + ((i0 < deg) ? i0 : (deg - 1))];
        float a0 = 0.f;
        if (i0 < deg) {
            float e = s1s[e0 * 8 + h] + sdh;
            e = (e > 0.f) ? e : 0.2f * e;
            a0 = __expf(e);
            dsum += a0;
        }
        // gather step 0 (edges chunk+0..3) -- always (deg >= chunk+1)
        {
            int   s0 = __shfl(e0, grp * 8);
            float w0 = __shfl(a0, grp * 8 + hc);
            h8v v0 = *(const h8v*)(h1h + (size_t)s0 * 128 + cidx * 8);
            #pragma unroll
            for (int j = 0; j < 8; ++j) acc[j] += w0 * (float)v0[j];
        }
        if (rem > 4) {   // step 1 (edges chunk+4..7)
            int   s1 = __shfl(e0, (4 + grp) * 8);
            float w1 = __shfl(a0, (4 + grp) * 8 + hc);
            h8v v1 = *(const h8v*)(h1h + (size_t)s1 * 128 + cidx * 8);
            #pragma unroll
            for (int j = 0; j < 8; ++j) acc[j] += w1 * (float)v1[j];
        }
        if (rem > 8) {   // second 8-edge exp sub-chunk + steps 2/3
            int i1 = chunk + 8 + slot;
            int e1 = csr_src[beg + ((i1 < deg) ? i1 : (deg - 1))];
            float a1 = 0.f;
            if (i1 < deg) {
                float e = s1s[e1 * 8 + h] + sdh;
                e = (e > 0.f) ? e : 0.2f * e;
                a1 = __expf(e);
                dsum += a1;
            }
            {
                int   s2 = __shfl(e1, grp * 8);
                float w2 = __shfl(a1, grp * 8 + hc);
                h8v v2 = *(const h8v*)(h1h + (size_t)s2 * 128 + cidx * 8);
                #pragma unroll
                for (int j = 0; j < 8; ++j) acc[j] += w2 * (float)v2[j];
            }
            if (rem > 12) {
                int   s3 = __shfl(e1, (4 + grp) * 8);
                float w3 = __shfl(a1, (4 + grp) * 8 + hc);
                h8v v3 = *(const h8v*)(h1h + (size_t)s3 * 128 + cidx * 8);
                #pragma unroll
                for (int j = 0; j < 8; ++j) acc[j] += w3 * (float)v3[j];
            }
        }
    }
    // denom: fold over slots; lane l holds head (l&7) total
    dsum += __shfl_xor(dsum, 8);
    dsum += __shfl_xor(dsum, 16);
    dsum += __shfl_xor(dsum, 32);
    float rd = 1.f / __shfl(dsum, hc);   // lane hc has h == hc
    // fold acc across the 4 gather groups
    #pragma unroll
    for (int j = 0; j < 8; ++j) {
        acc[j] += __shfl_xor(acc[j], 16);
        acc[j] += __shfl_xor(acc[j], 32);
    }
    // each group writes its 2-channel slice (fp16)
    int c0 = cidx * 8 + grp * 2;
    float va = acc[grp * 2] * rd + b1[c0];
    va = (va > 0.f) ? va : (__expf(va) - 1.f);
    float vb = acc[grp * 2 + 1] * rd + b1[c0 + 1];
    vb = (vb > 0.f) ? vb : (__expf(vb) - 1.f);
    *(__half2*)(h2o + (size_t)n * 128 + c0) = __floats2half2_rn(va, vb);
}

// ------- GEMM2: g2h(fp16) = h2(fp16) @ W2  (thread = node) + logits -------

__global__ __launch_bounds__(256) void k_gemm2(const __half* __restrict__ h2,
        const float* __restrict__ W2p,
        const float* __restrict__ a2s, const float* __restrict__ a2d,
        __half* __restrict__ g2h, float* __restrict__ s2s, float* __restrict__ s2d) {
    int n = blockIdx.x * 256 + threadIdx.x;
    bool valid = (n < N_NODES);
    int nn = valid ? n : (N_NODES - 1);
    const __half2* hrow = (const __half2*)(h2 + (size_t)nn * 128);
    float4 acc[12];
    #pragma unroll
    for (int j = 0; j < 12; ++j) acc[j] = make_float4(0.f, 0.f, 0.f, 0.f);
    #pragma unroll 1
    for (int k = 0; k < 128; k += 4) {
        float2 h01 = __half22float2(hrow[k / 2]);
        float2 h23 = __half22float2(hrow[k / 2 + 1]);
        float hk[4] = {h01.x, h01.y, h23.x, h23.y};
        #pragma unroll
        for (int kk = 0; kk < 4; ++kk) {
            const float* wrow = W2p + (size_t)(k + kk) * 48;
            #pragma unroll
            for (int j = 0; j < 12; ++j) {
                float4 wv = *(const float4*)(wrow + j * 4);
                acc[j].x += hk[kk] * wv.x;
                acc[j].y += hk[kk] * wv.y;
                acc[j].z += hk[kk] * wv.z;
                acc[j].w += hk[kk] * wv.w;
            }
        }
    }
    float vs = 0.f, vd = 0.f;
    #pragma unroll
    for (int j = 0; j < 12; ++j) {
        int c = j * 4;
        vs += acc[j].x * a2s[c + 0]; vd += acc[j].x * a2d[c + 0];
        vs += acc[j].y * a2s[c + 1]; vd += acc[j].y * a2d[c + 1];
        vs += acc[j].z * a2s[c + 2]; vd += acc[j].z * a2d[c + 2];
        if (j < 11) { vs += acc[j].w * a2s[c + 3]; vd += acc[j].w * a2d[c + 3]; }
    }
    if (valid) {
        __half2* orow = (__half2*)(g2h + (size_t)n * 48);
        #pragma unroll
        for (int j = 0; j < 12; ++j) {
            orow[j * 2 + 0] = __floats2half2_rn(acc[j].x, acc[j].y);
            orow[j * 2 + 1] = __floats2half2_rn(acc[j].z, acc[j].w);
        }
        s2s[n] = vs;
        s2d[n] = vd;
    }
}

// ------- layer-2 aggregate + bias + log_softmax (single fused pass) -------

__global__ __launch_bounds__(256) void k_agg2(const __half* __restrict__ g2h,
        const float* __restrict__ s2s, const float* __restrict__ s2d,
        const int* __restrict__ offs, const unsigned short* __restrict__ csr_src,
        const float* __restrict__ b2, float* __restrict__ outp) {
    int wave = threadIdx.x >> 6, lane = threadIdx.x & 63;
    int n = blockIdx.x * 4 + wave;
    int beg = offs[n];
    int deg = offs[n + 1] - beg;
    float sdn = s2d[n];
    int c = (lane < 47) ? lane : 47;   // col 47 is zero padding, valid address

    float dsum = 0.f;
    float acc = 0.f;
    for (int chunk = 0; chunk < deg; chunk += 64) {
        int i = chunk + lane;
        int esrc = csr_src[beg + ((i < deg) ? i : (deg - 1))];
        float aN = 0.f;
        if (i < deg) {
            float e = s2s[esrc] + sdn;
            e = (e > 0.f) ? e : 0.2f * e;
            aN = __expf(e);
            dsum += aN;
        }
        int lim = deg - chunk; if (lim > 64) lim = 64;
        for (int g = 0; g < lim; g += 8) {
            int   srcs[8];
            float as[8];
            #pragma unroll
            for (int s = 0; s < 8; ++s) {
                srcs[s] = __shfl(esrc, g + s);
                as[s]   = __shfl(aN, g + s);     // 0 for inactive
            }
            __half v[8];
            #pragma unroll
            for (int s = 0; s < 8; ++s) v[s] = g2h[(size_t)srcs[s] * 48 + c];
            #pragma unroll
            for (int s = 0; s < 8; ++s) acc += as[s] * __half2float(v[s]);
        }
    }
    #pragma unroll
    for (int o = 32; o; o >>= 1) dsum += __shfl_xor(dsum, o);
    acc *= 1.f / dsum;

    float l = (lane < 47) ? acc + b2[lane] : -1e30f;
    float rm = l;
    #pragma unroll
    for (int o = 32; o; o >>= 1) rm = fmaxf(rm, __shfl_xor(rm, o));
    float p = (lane < 47) ? __expf(l - rm) : 0.f;
    float ps = p;
    #pragma unroll
    for (int o = 32; o; o >>= 1) ps += __shfl_xor(ps, o);
    float lse = rm + __logf(ps);
    if (lane < 47) outp[(size_t)n * 47 + lane] = l - lse;
}

// ---------------- launcher ----------------

extern "C" void kernel_launch(void* const* d_in, const int* in_sizes, int n_in,
                              void* d_out, int out_size, void* d_ws, size_t ws_size,
                              hipStream_t stream) {
    const float* x   = (const float*)d_in[0];
    const int*   ei  = (const int*)d_in[1];
    const float* W1  = (const float*)d_in[2];
    const float* a1s = (const float*)d_in[3];
    const float* a1d = (const float*)d_in[4];
    const float* b1  = (const float*)d_in[5];
    const float* W2  = (const float*)d_in[6];
    const float* a2s = (const float*)d_in[7];
    const float* a2d = (const float*)d_in[8];
    const float* b2  = (const float*)d_in[9];
    float* outp = (float*)d_out;

    char* ws = (char*)d_ws;
    size_t off = 0;
    auto alloc = [&](size_t bytes) -> void* {
        void* p = ws + off;
        off += (bytes + 255) & ~(size_t)255;
        return p;
    };
    int* gh      = (int*)alloc((size_t)NBLKC * NBUCK * 4);
    int* tot     = (int*)alloc((size_t)NBUCK * 4);
    int* boff    = (int*)alloc((size_t)(NBUCK + 1) * 4);
    unsigned int* brec = (unsigned int*)alloc((size_t)E2 * 4);
    unsigned short* csr_src = (unsigned short*)alloc((size_t)E2 * 2);
    int* offs    = (int*)alloc((size_t)(N_NODES + 1) * 4);
    __half* h1h  = (__half*)alloc((size_t)N_NODES * 128 * 2);
    float* s1s   = (float*)alloc((size_t)N_NODES * 8 * 4);
    float* s1d   = (float*)alloc((size_t)N_NODES * 8 * 4);
    __half* h2h  = (__half*)alloc((size_t)N_NODES * 128 * 2);
    __half* g2h  = (__half*)alloc((size_t)N_NODES * 48 * 2);
    float* s2s   = (float*)alloc((size_t)N_NODES * 4);
    float* s2d   = (float*)alloc((size_t)N_NODES * 4);
    float* W2p   = (float*)alloc((size_t)128 * 48 * 4);
    _Float16* W1T = (_Float16*)alloc((size_t)128 * 256 * 2);

    (void)in_sizes; (void)n_in; (void)out_size; (void)ws_size;

    // CSR build + layer-1 front end (8 launches total)
    k_hist<<<NBLKC + 1, 256, 0, stream>>>(ei, gh, W1, W1T);
    k_csg<<<CSBLK + G1BLK, 256, 0, stream>>>(gh, tot, x, W1T, (_Float16*)h1h);
    k_mid<<<1 + (N_NODES * 8 + 255) / 256, 256, 0, stream>>>(tot, boff, W2, W2p,
                                                             h1h, a1s, a1d, s1s, s1d);
    k_place<<<NBLKC, 256, 0, stream>>>(ei, gh, boff, brec);
    k_finalize<<<NBUCK, 256, 0, stream>>>(brec, boff, csr_src, offs);

    k_agg1<<<N_NODES / 4, 256, 0, stream>>>(h1h, s1s, s1d, offs, csr_src, b1, h2h);
    k_gemm2<<<(N_NODES + 255) / 256, 256, 0, stream>>>(h2h, W2p, a2s, a2d, g2h, s2s, s2d);
    k_agg2<<<N_NODES / 4, 256, 0, stream>>>(g2h, s2s, s2d, offs, csr_src, b2, outp);
}

// Round 24
// 177.466 us; speedup vs baseline: 1.0198x; 1.0198x over previous
//
#include <hip/hip_runtime.h>
#include <hip/hip_fp16.h>

#define N_NODES 50000
#define N_EDGES 800000
#define E2 (N_EDGES + N_NODES)   // 850000 edges incl self-loops

#define BSHIFT 6
#define BMASK 63
#define NBUCK 782            // ceil(50000/64) buckets of 64 dst each
#define EPB 4096             // edges per block in counting sort
#define NBLKC 208            // ceil(E2/EPB)
#define CSBLK 196            // colscan blocks (4 buckets each)
#define G1BLK 391            // gemm1 blocks (128 rows each)

typedef _Float16 h8v __attribute__((ext_vector_type(8)));
typedef float f4v __attribute__((ext_vector_type(4)));

// ---------------- CSR build: counting sort (no global atomics) ----------------

// phase A: per-block LDS histogram -> gh[blk][b]; block NBLKC preps W1T
__global__ __launch_bounds__(256) void k_hist(const int* __restrict__ ei,
        int* __restrict__ gh, const float* __restrict__ W1, _Float16* __restrict__ W1T) {
    if (blockIdx.x == NBLKC) {   // W1 transpose+fp16: W1T[c][k] = W1[k][c]
        for (int i = threadIdx.x; i < 128 * 256; i += 256) {
            int c = i >> 8, k = i & 255;
            W1T[i] = (_Float16)W1[k * 128 + c];
        }
        return;
    }
    __shared__ int h[NBUCK];
    int tid = threadIdx.x;
    for (int b = tid; b < NBUCK; b += 256) h[b] = 0;
    __syncthreads();
    int base = blockIdx.x * EPB;
    for (int i = tid; i < EPB; i += 256) {
        int e = base + i;
        if (e < E2) {
            int dst = (e < N_EDGES) ? ei[N_EDGES + e] : (e - N_EDGES);
            atomicAdd(&h[dst >> BSHIFT], 1);
        }
    }
    __syncthreads();
    for (int b = tid; b < NBUCK; b += 256) gh[blockIdx.x * NBUCK + b] = h[b];
}

// fused: blocks [0,CSBLK) = colscan (per-bucket scan across blocks);
//        blocks [CSBLK, CSBLK+G1BLK) = GEMM1 MFMA (independent of CSR).
__global__ __launch_bounds__(256) void k_csg(int* __restrict__ gh,
        int* __restrict__ tot, const float* __restrict__ x,
        const _Float16* __restrict__ W1T, _Float16* __restrict__ h1h) {
    if (blockIdx.x < CSBLK) {
        // ---- colscan ----
        int wave = threadIdx.x >> 6, lane = threadIdx.x & 63;
        int b = blockIdx.x * 4 + wave;
        if (b >= NBUCK) return;
        int carry = 0;
        for (int c = 0; c < NBLKC; c += 64) {
            int k = c + lane;
            int v = (k < NBLKC) ? gh[k * NBUCK + b] : 0;
            int xv = v;
            #pragma unroll
            for (int o = 1; o < 64; o <<= 1) { int y = __shfl_up(xv, o); if (lane >= o) xv += y; }
            if (k < NBLKC) gh[k * NBUCK + b] = carry + xv - v;   // exclusive
            carry += __shfl(xv, 63);
        }
        if (lane == 0) tot[b] = carry;
        return;
    }
    // ---- GEMM1: 4 waves x 32 rows = 128 rows per block ----
    int gblk = blockIdx.x - CSBLK;
    int lane = threadIdx.x & 63;
    int wv = threadIdx.x >> 6;            // 0..3
    int rowbase = gblk * 128 + wv * 32;
    int r0 = lane & 15;
    int kg = lane >> 4;                   // 0..3
    f4v acc[2][8];
    #pragma unroll
    for (int i = 0; i < 2; ++i)
        #pragma unroll
        for (int j = 0; j < 8; ++j) acc[i][j] = (f4v)0.f;

    #pragma unroll 1
    for (int kt = 0; kt < 256; kt += 32) {
        h8v a[2];
        #pragma unroll
        for (int rf = 0; rf < 2; ++rf) {
            int row = rowbase + rf * 16 + r0;
            if (row >= N_NODES) row = N_NODES - 1;
            const float* ap = x + (size_t)row * 256 + kt + kg * 8;
            float4 lo = *(const float4*)ap;
            float4 hi = *(const float4*)(ap + 4);
            h8v t;
            t[0] = (_Float16)lo.x; t[1] = (_Float16)lo.y;
            t[2] = (_Float16)lo.z; t[3] = (_Float16)lo.w;
            t[4] = (_Float16)hi.x; t[5] = (_Float16)hi.y;
            t[6] = (_Float16)hi.z; t[7] = (_Float16)hi.w;
            a[rf] = t;
        }
        #pragma unroll
        for (int cf = 0; cf < 8; ++cf) {
            h8v b = *(const h8v*)(W1T + (size_t)(cf * 16 + r0) * 256 + kt + kg * 8);
            acc[0][cf] = __builtin_amdgcn_mfma_f32_16x16x32_f16(a[0], b, acc[0][cf], 0, 0, 0);
            acc[1][cf] = __builtin_amdgcn_mfma_f32_16x16x32_f16(a[1], b, acc[1][cf], 0, 0, 0);
        }
    }
    // C/D: col = lane&15, row = (lane>>4)*4 + reg
    #pragma unroll
    for (int rf = 0; rf < 2; ++rf) {
        #pragma unroll
        for (int r = 0; r < 4; ++r) {
            int row = rowbase + rf * 16 + kg * 4 + r;
            if (row < N_NODES) {
                _Float16* orow = h1h + (size_t)row * 128 + r0;
                #pragma unroll
                for (int cf = 0; cf < 8; ++cf)
                    orow[cf * 16] = (_Float16)acc[rf][cf][r];
            }
        }
    }
}

// fused: block 0 = btot (scan bucket totals -> boff, + W2 pad);
//        blocks >= 1 = logits1 (reads fp16 h1h).
__global__ __launch_bounds__(256) void k_mid(const int* __restrict__ tot,
        int* __restrict__ boff, const float* __restrict__ W2, float* __restrict__ W2p,
        const __half* __restrict__ h1h,
        const float* __restrict__ a1s, const float* __restrict__ a1d,
        float* __restrict__ s1s, float* __restrict__ s1d) {
    if (blockIdx.x == 0) {
        int t = threadIdx.x;
        for (int i = t; i < 128 * 48; i += 256) {
            int k = i / 48, c = i - k * 48;
            W2p[i] = (c < 47) ? W2[k * 47 + c] : 0.f;
        }
        int v4[4]; int s = 0;
        #pragma unroll
        for (int j = 0; j < 4; ++j) {
            int b2 = t * 4 + j;
            v4[j] = (b2 < NBUCK) ? tot[b2] : 0;
            s += v4[j];
        }
        int lane = t & 63, w = t >> 6;
        __shared__ int ws[4];
        int xv = s;
        #pragma unroll
        for (int o = 1; o < 64; o <<= 1) { int y = __shfl_up(xv, o); if (lane >= o) xv += y; }
        if (lane == 63) ws[w] = xv;
        __syncthreads();
        int add = 0;
        for (int j = 0; j < w; ++j) add += ws[j];
        int run = add + xv - s;
        #pragma unroll
        for (int j = 0; j < 4; ++j) {
            int b2 = t * 4 + j;
            if (b2 < NBUCK) boff[b2] = run;
            run += v4[j];
        }
        if (t == 255) boff[NBUCK] = run;   // == E2
        return;
    }
    int idx = (blockIdx.x - 1) * 256 + threadIdx.x;   // N*8
    if (idx >= N_NODES * 8) return;
    int n = idx >> 3, h = idx & 7;
    const __half2* hp2 = (const __half2*)(h1h + (size_t)n * 128 + h * 16);
    float ss = 0.f, sd = 0.f;
    #pragma unroll
    for (int c2 = 0; c2 < 8; ++c2) {
        float2 v = __half22float2(hp2[c2]);
        ss += v.x * a1s[h * 16 + 2 * c2] + v.y * a1s[h * 16 + 2 * c2 + 1];
        sd += v.x * a1d[h * 16 + 2 * c2] + v.y * a1d[h * 16 + 2 * c2 + 1];
    }
    s1s[idx] = ss;
    s1d[idx] = sd;
}

// phase C: deterministic placement (LDS ranks only)
__global__ __launch_bounds__(256) void k_place(const int* __restrict__ ei,
        const int* __restrict__ gh, const int* __restrict__ boff,
        unsigned int* __restrict__ brec) {
    __shared__ int sbase[NBUCK];
    __shared__ int cnt[NBUCK];
    int tid = threadIdx.x;
    for (int b = tid; b < NBUCK; b += 256) {
        sbase[b] = boff[b] + gh[blockIdx.x * NBUCK + b];
        cnt[b] = 0;
    }
    __syncthreads();
    int base = blockIdx.x * EPB;
    for (int i = tid; i < EPB; i += 256) {
        int e = base + i;
        if (e < E2) {
            int src, dst;
            if (e < N_EDGES) { src = ei[e]; dst = ei[N_EDGES + e]; }
            else             { src = dst = e - N_EDGES; }
            int b = dst >> BSHIFT;
            int r = atomicAdd(&cnt[b], 1);
            brec[sbase[b] + r] = ((unsigned int)(dst & BMASK) << 16) | (unsigned int)src;
        }
    }
}

// per-bucket finalize: LDS histogram/scan/scatter -> coalesced csr write + offs
__global__ __launch_bounds__(256) void k_finalize(const unsigned int* __restrict__ brec,
        const int* __restrict__ boff, unsigned short* __restrict__ csr_src,
        int* __restrict__ offs) {
    int B = blockIdx.x;
    int tid = threadIdx.x;
    int base = boff[B];
    int total = boff[B + 1] - base;
    __shared__ int hist[64], cur[64];
    __shared__ unsigned short stage[2048];
    if (tid < 64) hist[tid] = 0;
    __syncthreads();
    const unsigned int* bp = brec + base;
    for (int i = tid; i < total; i += 256) atomicAdd(&hist[bp[i] >> 16], 1);
    __syncthreads();
    if (tid < 64) {   // wave 0: exclusive scan over 64 node-counts
        int v = hist[tid];
        int x = v;
        #pragma unroll
        for (int o = 1; o < 64; o <<= 1) { int y = __shfl_up(x, o); if (tid >= o) x += y; }
        int excl = x - v;
        cur[tid] = excl;
        int n = B * 64 + tid;
        if (n < N_NODES) offs[n] = base + excl;
    }
    if (B == NBUCK - 1 && tid == 0) offs[N_NODES] = boff[NBUCK];
    __syncthreads();
    if (total <= 2048) {
        for (int i = tid; i < total; i += 256) {
            unsigned int r = bp[i];
            int p = atomicAdd(&cur[r >> 16], 1);
            stage[p] = (unsigned short)(r & 0xFFFFu);
        }
        __syncthreads();
        for (int i = tid; i < total; i += 256) csr_src[base + i] = stage[i];
    } else {   // safety fallback (never hit for this graph)
        for (int i = tid; i < total; i += 256) {
            unsigned int r = bp[i];
            int p = atomicAdd(&cur[r >> 16], 1);
            csr_src[base + p] = (unsigned short)(r & 0xFFFFu);
        }
    }
}

// ------- layer-1 aggregate + bias + ELU (wave per node) -------
// 16-edge chunks: 4 gather rows in flight per lane (unconditional, best-measured).

__global__ __launch_bounds__(256) void k_agg1(const __half* __restrict__ h1h,
        const float* __restrict__ s1s, const float* __restrict__ s1d,
        const int* __restrict__ offs, const unsigned short* __restrict__ csr_src,
        const float* __restrict__ b1, __half* __restrict__ h2o) {
    int wave = threadIdx.x >> 6;
    int lane = threadIdx.x & 63;
    int n = blockIdx.x * 4 + wave;   // N = 4*12500 exactly
    int beg = offs[n];
    int deg = offs[n + 1] - beg;     // >= 1 (self-loop)

    int h = lane & 7;        // head this lane evaluates exp for
    int slot = lane >> 3;    // edge slot within 8-sub-chunk (exp phase)
    int grp = lane >> 4;     // gather group 0..3
    int cidx = lane & 15;    // 16B channel block within row
    int hc = cidx >> 1;      // head of this lane's 8 channels
    float sdh = s1d[n * 8 + h];

    float dsum = 0.f;
    float acc[8] = {0.f, 0.f, 0.f, 0.f, 0.f, 0.f, 0.f, 0.f};
    for (int chunk = 0; chunk < deg; chunk += 16) {
        int i0 = chunk + slot;
        int i1 = chunk + 8 + slot;
        int e0 = csr_src[beg + ((i0 < deg) ? i0 : (deg - 1))];
        int e1 = csr_src[beg + ((i1 < deg) ? i1 : (deg - 1))];
        float a0 = 0.f, a1 = 0.f;
        if (i0 < deg) {
            float e = s1s[e0 * 8 + h] + sdh;
            e = (e > 0.f) ? e : 0.2f * e;
            a0 = __expf(e);
            dsum += a0;
        }
        if (i1 < deg) {
            float e = s1s[e1 * 8 + h] + sdh;
            e = (e > 0.f) ? e : 0.2f * e;
            a1 = __expf(e);
            dsum += a1;
        }
        // 4 gather steps; each 16-lane group reads one row (16B/lane)
        int   s0 = __shfl(e0, grp * 8);       float w0 = __shfl(a0, grp * 8 + hc);
        int   s1 = __shfl(e0, (4 + grp) * 8); float w1 = __shfl(a0, (4 + grp) * 8 + hc);
        int   s2 = __shfl(e1, grp * 8);       float w2 = __shfl(a1, grp * 8 + hc);
        int   s3 = __shfl(e1, (4 + grp) * 8); float w3 = __shfl(a1, (4 + grp) * 8 + hc);
        h8v v0 = *(const h8v*)(h1h + (size_t)s0 * 128 + cidx * 8);
        h8v v1 = *(const h8v*)(h1h + (size_t)s1 * 128 + cidx * 8);
        h8v v2 = *(const h8v*)(h1h + (size_t)s2 * 128 + cidx * 8);
        h8v v3 = *(const h8v*)(h1h + (size_t)s3 * 128 + cidx * 8);
        #pragma unroll
        for (int j = 0; j < 8; ++j) acc[j] += w0 * (float)v0[j];
        #pragma unroll
        for (int j = 0; j < 8; ++j) acc[j] += w1 * (float)v1[j];
        #pragma unroll
        for (int j = 0; j < 8; ++j) acc[j] += w2 * (float)v2[j];
        #pragma unroll
        for (int j = 0; j < 8; ++j) acc[j] += w3 * (float)v3[j];
    }
    // denom: fold over slots; lane l holds head (l&7) total
    dsum += __shfl_xor(dsum, 8);
    dsum += __shfl_xor(dsum, 16);
    dsum += __shfl_xor(dsum, 32);
    float rd = 1.f / __shfl(dsum, hc);   // lane hc has h == hc
    // fold acc across the 4 gather groups
    #pragma unroll
    for (int j = 0; j < 8; ++j) {
        acc[j] += __shfl_xor(acc[j], 16);
        acc[j] += __shfl_xor(acc[j], 32);
    }
    // each group writes its 2-channel slice (fp16)
    int c0 = cidx * 8 + grp * 2;
    float va = acc[grp * 2] * rd + b1[c0];
    va = (va > 0.f) ? va : (__expf(va) - 1.f);
    float vb = acc[grp * 2 + 1] * rd + b1[c0 + 1];
    vb = (vb > 0.f) ? vb : (__expf(vb) - 1.f);
    *(__half2*)(h2o + (size_t)n * 128 + c0) = __floats2half2_rn(va, vb);
}

// ------- GEMM2: g2h(fp16) = h2(fp16) @ W2  (thread = node) + logits -------

__global__ __launch_bounds__(256) void k_gemm2(const __half* __restrict__ h2,
        const float* __restrict__ W2p,
        const float* __restrict__ a2s, const float* __restrict__ a2d,
        __half* __restrict__ g2h, float* __restrict__ s2s, float* __restrict__ s2d) {
    int n = blockIdx.x * 256 + threadIdx.x;
    bool valid = (n < N_NODES);
    int nn = valid ? n : (N_NODES - 1);
    const __half2* hrow = (const __half2*)(h2 + (size_t)nn * 128);
    float4 acc[12];
    #pragma unroll
    for (int j = 0; j < 12; ++j) acc[j] = make_float4(0.f, 0.f, 0.f, 0.f);
    #pragma unroll 1
    for (int k = 0; k < 128; k += 4) {
        float2 h01 = __half22float2(hrow[k / 2]);
        float2 h23 = __half22float2(hrow[k / 2 + 1]);
        float hk[4] = {h01.x, h01.y, h23.x, h23.y};
        #pragma unroll
        for (int kk = 0; kk < 4; ++kk) {
            const float* wrow = W2p + (size_t)(k + kk) * 48;
            #pragma unroll
            for (int j = 0; j < 12; ++j) {
                float4 wv = *(const float4*)(wrow + j * 4);
                acc[j].x += hk[kk] * wv.x;
                acc[j].y += hk[kk] * wv.y;
                acc[j].z += hk[kk] * wv.z;
                acc[j].w += hk[kk] * wv.w;
            }
        }
    }
    float vs = 0.f, vd = 0.f;
    #pragma unroll
    for (int j = 0; j < 12; ++j) {
        int c = j * 4;
        vs += acc[j].x * a2s[c + 0]; vd += acc[j].x * a2d[c + 0];
        vs += acc[j].y * a2s[c + 1]; vd += acc[j].y * a2d[c + 1];
        vs += acc[j].z * a2s[c + 2]; vd += acc[j].z * a2d[c + 2];
        if (j < 11) { vs += acc[j].w * a2s[c + 3]; vd += acc[j].w * a2d[c + 3]; }
    }
    if (valid) {
        __half2* orow = (__half2*)(g2h + (size_t)n * 48);
        #pragma unroll
        for (int j = 0; j < 12; ++j) {
            orow[j * 2 + 0] = __floats2half2_rn(acc[j].x, acc[j].y);
            orow[j * 2 + 1] = __floats2half2_rn(acc[j].z, acc[j].w);
        }
        s2s[n] = vs;
        s2d[n] = vd;
    }
}

// ------- layer-2 aggregate + bias + log_softmax (single fused pass) -------

__global__ __launch_bounds__(256) void k_agg2(const __half* __restrict__ g2h,
        const float* __restrict__ s2s, const float* __restrict__ s2d,
        const int* __restrict__ offs, const unsigned short* __restrict__ csr_src,
        const float* __restrict__ b2, float* __restrict__ outp) {
    int wave = threadIdx.x >> 6, lane = threadIdx.x & 63;
    int n = blockIdx.x * 4 + wave;
    int beg = offs[n];
    int deg = offs[n + 1] - beg;
    float sdn = s2d[n];
    int c = (lane < 47) ? lane : 47;   // col 47 is zero padding, valid address

    float dsum = 0.f;
    float acc = 0.f;
    for (int chunk = 0; chunk < deg; chunk += 64) {
        int i = chunk + lane;
        int esrc = csr_src[beg + ((i < deg) ? i : (deg - 1))];
        float aN = 0.f;
        if (i < deg) {
            float e = s2s[esrc] + sdn;
            e = (e > 0.f) ? e : 0.2f * e;
            aN = __expf(e);
            dsum += aN;
        }
        int lim = deg - chunk; if (lim > 64) lim = 64;
        for (int g = 0; g < lim; g += 8) {
            int   srcs[8];
            float as[8];
            #pragma unroll
            for (int s = 0; s < 8; ++s) {
                srcs[s] = __shfl(esrc, g + s);
                as[s]   = __shfl(aN, g + s);     // 0 for inactive
            }
            __half v[8];
            #pragma unroll
            for (int s = 0; s < 8; ++s) v[s] = g2h[(size_t)srcs[s] * 48 + c];
            #pragma unroll
            for (int s = 0; s < 8; ++s) acc += as[s] * __half2float(v[s]);
        }
    }
    #pragma unroll
    for (int o = 32; o; o >>= 1) dsum += __shfl_xor(dsum, o);
    acc *= 1.f / dsum;

    float l = (lane < 47) ? acc + b2[lane] : -1e30f;
    float rm = l;
    #pragma unroll
    for (int o = 32; o; o >>= 1) rm = fmaxf(rm, __shfl_xor(rm, o));
    float p = (lane < 47) ? __expf(l - rm) : 0.f;
    float ps = p;
    #pragma unroll
    for (int o = 32; o; o >>= 1) ps += __shfl_xor(ps, o);
    float lse = rm + __logf(ps);
    if (lane < 47) outp[(size_t)n * 47 + lane] = l - lse;
}

// ---------------- launcher ----------------

extern "C" void kernel_launch(void* const* d_in, const int* in_sizes, int n_in,
                              void* d_out, int out_size, void* d_ws, size_t ws_size,
                              hipStream_t stream) {
    const float* x   = (const float*)d_in[0];
    const int*   ei  = (const int*)d_in[1];
    const float* W1  = (const float*)d_in[2];
    const float* a1s = (const float*)d_in[3];
    const float* a1d = (const float*)d_in[4];
    const float* b1  = (const float*)d_in[5];
    const float* W2  = (const float*)d_in[6];
    const float* a2s = (const float*)d_in[7];
    const float* a2d = (const float*)d_in[8];
    const float* b2  = (const float*)d_in[9];
    float* outp = (float*)d_out;

    char* ws = (char*)d_ws;
    size_t off = 0;
    auto alloc = [&](size_t bytes) -> void* {
        void* p = ws + off;
        off += (bytes + 255) & ~(size_t)255;
        return p;
    };
    int* gh      = (int*)alloc((size_t)NBLKC * NBUCK * 4);
    int* tot     = (int*)alloc((size_t)NBUCK * 4);
    int* boff    = (int*)alloc((size_t)(NBUCK + 1) * 4);
    unsigned int* brec = (unsigned int*)alloc((size_t)E2 * 4);
    unsigned short* csr_src = (unsigned short*)alloc((size_t)E2 * 2);
    int* offs    = (int*)alloc((size_t)(N_NODES + 1) * 4);
    __half* h1h  = (__half*)alloc((size_t)N_NODES * 128 * 2);
    float* s1s   = (float*)alloc((size_t)N_NODES * 8 * 4);
    float* s1d   = (float*)alloc((size_t)N_NODES * 8 * 4);
    __half* h2h  = (__half*)alloc((size_t)N_NODES * 128 * 2);
    __half* g2h  = (__half*)alloc((size_t)N_NODES * 48 * 2);
    float* s2s   = (float*)alloc((size_t)N_NODES * 4);
    float* s2d   = (float*)alloc((size_t)N_NODES * 4);
    float* W2p   = (float*)alloc((size_t)128 * 48 * 4);
    _Float16* W1T = (_Float16*)alloc((size_t)128 * 256 * 2);

    (void)in_sizes; (void)n_in; (void)out_size; (void)ws_size;

    // CSR build + layer-1 front end (8 launches total)
    k_hist<<<NBLKC + 1, 256, 0, stream>>>(ei, gh, W1, W1T);
    k_csg<<<CSBLK + G1BLK, 256, 0, stream>>>(gh, tot, x, W1T, (_Float16*)h1h);
    k_mid<<<1 + (N_NODES * 8 + 255) / 256, 256, 0, stream>>>(tot, boff, W2, W2p,
                                                             h1h, a1s, a1d, s1s, s1d);
    k_place<<<NBLKC, 256, 0, stream>>>(ei, gh, boff, brec);
    k_finalize<<<NBUCK, 256, 0, stream>>>(brec, boff, csr_src, offs);

    k_agg1<<<N_NODES / 4, 256, 0, stream>>>(h1h, s1s, s1d, offs, csr_src, b1, h2h);
    k_gemm2<<<(N_NODES + 255) / 256, 256, 0, stream>>>(h2h, W2p, a2s, a2d, g2h, s2s, s2d);
    k_agg2<<<N_NODES / 4, 256, 0, stream>>>(g2h, s2s, s2d, offs, csr_src, b2, outp);
}